// Round 6
// baseline (98.252 us; speedup 1.0000x reference)
//
#include <hip/hip_runtime.h>

#define HH 512
#define DD 64
#define MROWS 64
#define TPB 1024
#define LP 520            // u16 pitch for 64x512 LDS tiles

typedef unsigned short u16;
typedef short s16x8 __attribute__((ext_vector_type(8)));   // 8 bf16 = 4 VGPRs
typedef float f32x4 __attribute__((ext_vector_type(4)));

#define MFMA16(A,B,C) __builtin_amdgcn_mfma_f32_16x16x32_bf16((A),(B),(C),0,0,0)

// ---- workspace layout (u16 element offsets), fragment-linear:
//   addr = ntile*16*K + ks*512 + lane*8 ; value[j] = M[k = ks*32+(lane>>4)*8+j][n = nt*16+(lane&15)]
#define OFF_EF   0
#define OFF_W2F  (HH*HH)
#define OFF_W1F  (2*HH*HH)
#define OFF_W3F  (2*HH*HH + HH*DD)
#define OFF_Z0B  ((2*HH*HH + 2*HH*DD)*2)   // byte offset of z0 (f32[512])

__device__ __forceinline__ u16 f2bf(float f) {
    unsigned u = __builtin_bit_cast(unsigned, f);
    u += 0x7fffu + ((u >> 16) & 1u);
    return (u16)(u >> 16);
}
__device__ __forceinline__ float bf2f(u16 h) {
    return __builtin_bit_cast(float, (unsigned)h << 16);
}
__device__ __forceinline__ float fast_tanh(float x) {
    float e = __expf(2.0f * x);
    return 1.0f - 2.0f * __builtin_amdgcn_rcpf(e + 1.0f);
}

// =======================================================================
// precompute: 137 blocks x 256 threads (unchanged from R4 — ~4 us)
// =======================================================================
__global__ __launch_bounds__(256) void precompute(
    const float* __restrict__ t,  const float* __restrict__ W1,
    const float* __restrict__ b1, const float* __restrict__ W2,
    const float* __restrict__ W3, u16* __restrict__ ws16, float* __restrict__ z0)
{
    __shared__ float T[16 * 264 > 256 * 20 ? 16 * 264 : 256 * 20];
    u16* Ef  = ws16 + OFF_EF;
    u16* W2f = ws16 + OFF_W2F;
    u16* W1f = ws16 + OFF_W1F;
    u16* W3f = ws16 + OFF_W3F;

    const int bid = blockIdx.x, tid = threadIdx.x;
    const int lane = tid & 63, wv = tid >> 6;
    const int m16 = lane & 15, q = lane >> 4;

    if (bid < 64) {
        const int nt = bid >> 1, bh = bid & 1;
        const int a0 = nt * 16, b0 = bh * 256;
        s16x8 afh[2], afl[2];
#pragma unroll
        for (int h = 0; h < 2; ++h)
#pragma unroll
            for (int j = 0; j < 8; ++j) {
                int i = h * 32 + q * 8 + j;
                float v = W1[(1 + i) * HH + a0 + m16];
                u16 hi = f2bf(v);
                afh[h][j] = (short)hi;
                afl[h][j] = (short)f2bf(v - bf2f(hi));
            }
#pragma unroll
        for (int bt = 0; bt < 4; ++bt) {
            int bl = wv * 64 + bt * 16;
            s16x8 bfh[2], bfl[2];
#pragma unroll
            for (int h = 0; h < 2; ++h) {
                const float* src = W3 + (b0 + bl + m16) * DD + h * 32 + q * 8;
                float4 p0 = *(const float4*)(src);
                float4 p1 = *(const float4*)(src + 4);
                float vv[8] = {p0.x,p0.y,p0.z,p0.w,p1.x,p1.y,p1.z,p1.w};
#pragma unroll
                for (int j = 0; j < 8; ++j) {
                    u16 hi = f2bf(vv[j]);
                    bfh[h][j] = (short)hi;
                    bfl[h][j] = (short)f2bf(vv[j] - bf2f(hi));
                }
            }
            f32x4 c = {0.f, 0.f, 0.f, 0.f};
#pragma unroll
            for (int h = 0; h < 2; ++h) {
                c = MFMA16(afh[h], bfh[h], c);
                c = MFMA16(afh[h], bfl[h], c);
                c = MFMA16(afl[h], bfh[h], c);
            }
#pragma unroll
            for (int r = 0; r < 4; ++r)
                T[(4 * q + r) * 264 + bl + m16] = c[r];
        }
        __syncthreads();
#pragma unroll
        for (int p = 0; p < 2; ++p) {
            int ksl = p * 4 + wv;
            int al  = m16;
            int blc = ksl * 32 + q * 8;
            const float* w2p = W2 + (a0 + al) * HH + b0 + blc;
            float4 wa = *(const float4*)(w2p), wb = *(const float4*)(w2p + 4);
            const float* glp = T + al * 264 + blc;
            s16x8 o;
            o[0]=(short)f2bf(wa.x*glp[0]); o[1]=(short)f2bf(wa.y*glp[1]);
            o[2]=(short)f2bf(wa.z*glp[2]); o[3]=(short)f2bf(wa.w*glp[3]);
            o[4]=(short)f2bf(wb.x*glp[4]); o[5]=(short)f2bf(wb.y*glp[5]);
            o[6]=(short)f2bf(wb.z*glp[6]); o[7]=(short)f2bf(wb.w*glp[7]);
            *(s16x8*)(Ef + nt * 8192 + (b0 / 32 + ksl) * 512 + lane * 8) = o;
        }
        if (bh == 0 && tid < 128) {
            int ks = tid >> 6, ln = tid & 63;
            int n  = nt * 16 + (ln & 15);
            int k0 = ks * 32 + (ln >> 4) * 8;
            s16x8 o;
#pragma unroll
            for (int j = 0; j < 8; ++j) o[j] = (short)f2bf(W1[(1 + k0 + j) * HH + n]);
            *(s16x8*)(W1f + nt * 1024 + ks * 512 + ln * 8) = o;
        }
    } else if (bid < 128) {
        const int nt = (bid - 64) >> 1, kh = (bid - 64) & 1;
        const int n0 = nt * 16, k0 = kh * 256;
#pragma unroll
        for (int it = 0; it < 4; ++it) {
            int r = (tid >> 2) + it * 64;
            int c = (tid & 3) * 4;
            float4 v = *(const float4*)(W2 + (k0 + r) * HH + n0 + c);
            *(float4*)(T + r * 20 + c) = v;
        }
        __syncthreads();
#pragma unroll
        for (int p = 0; p < 2; ++p) {
            int ksl = p * 4 + wv;
            int kq  = ksl * 32 + q * 8;
            s16x8 o;
#pragma unroll
            for (int j = 0; j < 8; ++j) o[j] = (short)f2bf(T[(kq + j) * 20 + m16]);
            *(s16x8*)(W2f + nt * 8192 + (k0 / 32 + ksl) * 512 + lane * 8) = o;
        }
    } else if (bid < 136) {
        const int ot = (bid - 128) >> 1, kh = (bid - 128) & 1;
        const int o0 = ot * 16, k0 = kh * 256;
#pragma unroll
        for (int it = 0; it < 4; ++it) {
            int r = (tid >> 2) + it * 64;
            int c = (tid & 3) * 4;
            float4 v = *(const float4*)(W3 + (k0 + r) * DD + o0 + c);
            *(float4*)(T + r * 20 + c) = v;
        }
        __syncthreads();
#pragma unroll
        for (int p = 0; p < 2; ++p) {
            int ksl = p * 4 + wv;
            int kq  = ksl * 32 + q * 8;
            s16x8 o;
#pragma unroll
            for (int j = 0; j < 8; ++j) o[j] = (short)f2bf(T[(kq + j) * 20 + m16]);
            *(s16x8*)(W3f + ot * 8192 + (k0 / 32 + ksl) * 512 + lane * 8) = o;
        }
    } else {
        for (int n = tid; n < HH; n += 256)
            z0[n] = b1[n] + t[0] * W1[n];
    }
}

// =======================================================================
// cnf_main: 128 blocks x 1024 threads, 64 rows/block
//   halves aggregate weight traffic vs MROWS=32; 8 MFMA per B-load pair
// =======================================================================
__global__ __launch_bounds__(TPB) void cnf_main(
    const float* __restrict__ x,  const u16* __restrict__ ws16,
    const float* __restrict__ z0, const float* __restrict__ b2,
    const float* __restrict__ b3, float* __restrict__ out)
{
    __shared__ u16 h1s[MROWS * LP];     // h1 (alive through phase 4: d1 source)
    __shared__ u16 h2s[MROWS * LP];     // xs -> h2 -> d2 (in place)
    __shared__ float z0s[HH];
    __shared__ float b2s[HH];
    __shared__ float b3s[DD];
    __shared__ float divacc[16][MROWS];

    const u16* Ef  = ws16 + OFF_EF;
    const u16* W2f = ws16 + OFF_W2F;
    const u16* W1f = ws16 + OFF_W1F;
    const u16* W3f = ws16 + OFF_W3F;

    const int tid  = threadIdx.x;
    const int lane = tid & 63;
    const int w    = tid >> 6;        // 16 waves
    const int m16  = lane & 15;
    const int q    = lane >> 4;
    const int kq   = q * 8;
    const int n1   = w * 32;          // wave's 32-col slice (phases 1,2,4)
    const int r0   = blockIdx.x * MROWS;

    u16* xs = h2s;                    // xs (64 x pitch72) dead after phase 1

    // ---- top-of-kernel global prefetch: W1f frags + phase-2 first 4 k-steps ----
    s16x8 p1b[2][2];
#pragma unroll
    for (int ct = 0; ct < 2; ++ct) {
        const u16* bb = W1f + (w * 2 + ct) * 1024 + lane * 8;
        p1b[ct][0] = *(const s16x8*)(bb);
        p1b[ct][1] = *(const s16x8*)(bb + 512);
    }
    const u16* w2bp0 = W2f + (2 * w + 0) * 8192 + lane * 8;
    const u16* w2bp1 = W2f + (2 * w + 1) * 8192 + lane * 8;
    s16x8 B0[4], B1[4];
#pragma unroll
    for (int k = 0; k < 4; ++k) {
        B0[k] = *(const s16x8*)(w2bp0 + k * 512);
        B1[k] = *(const s16x8*)(w2bp1 + k * 512);
    }

    // ---- stage x (64 rows x 64 cols) into xs, plus z0/b2/b3 ----
    for (int idx = tid; idx < MROWS * DD; idx += TPB) {
        int r = idx >> 6, c = idx & 63;
        xs[r * 72 + c] = f2bf(x[(r0 + r) * (DD + 1) + c]);
    }
    if (tid < HH) { z0s[tid] = z0[tid]; b2s[tid] = b2[tid]; }
    if (tid < DD) b3s[tid] = b3[tid];
    __syncthreads();

    // ---- phase 1: h1 = tanh([t,x]@W1 + z0), K=64, 4 row-tiles ----
    {
        s16x8 xa[4][2];
#pragma unroll
        for (int rt = 0; rt < 4; ++rt)
#pragma unroll
            for (int h = 0; h < 2; ++h)
                xa[rt][h] = *(const s16x8*)(xs + (rt * 16 + m16) * 72 + h * 32 + kq);
        float h1v[4][2][4];
#pragma unroll
        for (int ct = 0; ct < 2; ++ct) {
            int col = n1 + ct * 16 + m16;
#pragma unroll
            for (int rt = 0; rt < 4; ++rt) {
                f32x4 c = {0.f, 0.f, 0.f, 0.f};
                c = MFMA16(xa[rt][0], p1b[ct][0], c);
                c = MFMA16(xa[rt][1], p1b[ct][1], c);
#pragma unroll
                for (int i = 0; i < 4; ++i)
                    h1v[rt][ct][i] = fast_tanh(c[i] + z0s[col]);
            }
        }
        __syncthreads();               // xs fully consumed before h1s... (separate buffers; but h2s=xs reused later)
#pragma unroll
        for (int ct = 0; ct < 2; ++ct) {
            int col = n1 + ct * 16 + m16;
#pragma unroll
            for (int rt = 0; rt < 4; ++rt)
#pragma unroll
                for (int i = 0; i < 4; ++i)
                    h1s[(rt * 16 + 4 * q + i) * LP + col] = f2bf(h1v[rt][ct][i]);
        }
    }
    __syncthreads();

    // ---- phase 2: h2 = tanh(h1@W2 + b2), 4 row-tiles x 2 n-tiles ----
    f32x4 acc[4][2];
#pragma unroll
    for (int rt = 0; rt < 4; ++rt)
#pragma unroll
        for (int ct = 0; ct < 2; ++ct) acc[rt][ct] = f32x4{0.f,0.f,0.f,0.f};
    {
#pragma unroll
        for (int ks = 0; ks < 16; ++ks) {
            const int sl = ks & 3;
            s16x8 f[4];
#pragma unroll
            for (int rt = 0; rt < 4; ++rt)
                f[rt] = *(const s16x8*)(h1s + (rt * 16 + m16) * LP + ks * 32 + kq);
#pragma unroll
            for (int rt = 0; rt < 4; ++rt) {
                acc[rt][0] = MFMA16(f[rt], B0[sl], acc[rt][0]);
                acc[rt][1] = MFMA16(f[rt], B1[sl], acc[rt][1]);
            }
            if (ks < 12) {
                B0[sl] = *(const s16x8*)(w2bp0 + (ks + 4) * 512);
                B1[sl] = *(const s16x8*)(w2bp1 + (ks + 4) * 512);
            }
        }
    }

    // ---- prefetch phase-3 W3 frags (independent of h2s) ----
    const int rowt = w >> 2, ot = w & 3;
    const u16* w3bp = W3f + ot * 8192 + lane * 8;
    s16x8 W3r[4];
#pragma unroll
    for (int k = 0; k < 4; ++k) W3r[k] = *(const s16x8*)(w3bp + k * 512);

    // ---- phase-2 epilogue: tanh -> h2s (xs region now dead) ----
#pragma unroll
    for (int rt = 0; rt < 4; ++rt)
#pragma unroll
        for (int ct = 0; ct < 2; ++ct) {
            int col = n1 + ct * 16 + m16;
#pragma unroll
            for (int i = 0; i < 4; ++i)
                h2s[(rt * 16 + 4 * q + i) * LP + col] = f2bf(fast_tanh(acc[rt][ct][i] + b2s[col]));
        }
    __syncthreads();

    // ---- phase 3 (all 16 waves: 4 rowt x 4 ot): dx = h2@W3 + b3 ----
    {
        const u16* ap = h2s + (rowt * 16 + m16) * LP + kq;
        f32x4 cA = {0.f,0.f,0.f,0.f}, cB = {0.f,0.f,0.f,0.f};
#pragma unroll
        for (int ks = 0; ks < 16; ++ks) {
            s16x8 fA = *(const s16x8*)(ap + ks * 32);
            const int sl = ks & 3;
            if (ks & 1) cB = MFMA16(fA, W3r[sl], cB);
            else        cA = MFMA16(fA, W3r[sl], cA);
            if (ks < 12) W3r[sl] = *(const s16x8*)(w3bp + (ks + 4) * 512);
        }
        f32x4 c3 = cA + cB;
        int o = ot * 16 + m16;
#pragma unroll
        for (int i = 0; i < 4; ++i)
            out[(r0 + rowt * 16 + 4 * q + i) * (DD + 1) + o] = c3[i] + b3s[o];
    }

    // ---- prefetch phase-4 Ef (depth 2, independent of conversion) ----
    const u16* efp0 = Ef + (2 * w + 0) * 8192 + lane * 8;
    const u16* efp1 = Ef + (2 * w + 1) * 8192 + lane * 8;
    s16x8 E0[4], E1[4];
#pragma unroll
    for (int k = 0; k < 2; ++k) {
        E0[k] = *(const s16x8*)(efp0 + k * 512);
        E1[k] = *(const s16x8*)(efp1 + k * 512);
    }
    __syncthreads();                   // phase 3 done reading h2s

    // ---- conversion: h2s -> d2 = 1 - h2^2, in place, vectorized ----
#pragma unroll
    for (int v = 0; v < 4; ++v) {
        int vi  = tid + v * TPB;        // 4096 vec8 groups
        int row = vi >> 6, colv = (vi & 63) * 8;
        u16* p = h2s + row * LP + colv;
        s16x8 hv = *(const s16x8*)p;
        s16x8 dv;
#pragma unroll
        for (int j = 0; j < 8; ++j) {
            float f = bf2f((u16)hv[j]);
            dv[j] = (short)f2bf(1.0f - f * f);
        }
        *(s16x8*)p = dv;
    }
    __syncthreads();

    // ---- phase 4: M = d2@Ef ; div = sum_col d1 .* M ----
    {
        f32x4 g[4][2];
#pragma unroll
        for (int rt = 0; rt < 4; ++rt)
#pragma unroll
            for (int ct = 0; ct < 2; ++ct) g[rt][ct] = f32x4{0.f,0.f,0.f,0.f};
#pragma unroll
        for (int ks = 0; ks < 16; ++ks) {
            const int sl = ks & 3;
            s16x8 f[4];
#pragma unroll
            for (int rt = 0; rt < 4; ++rt)
                f[rt] = *(const s16x8*)(h2s + (rt * 16 + m16) * LP + ks * 32 + kq);
#pragma unroll
            for (int rt = 0; rt < 4; ++rt) {
                g[rt][0] = MFMA16(f[rt], E0[sl], g[rt][0]);
                g[rt][1] = MFMA16(f[rt], E1[sl], g[rt][1]);
            }
            if (ks < 14) {
                const int dl = (ks + 2) & 3;
                E0[dl] = *(const s16x8*)(efp0 + (ks + 2) * 512);
                E1[dl] = *(const s16x8*)(efp1 + (ks + 2) * 512);
            }
        }
        // d1 from h1s, combine, lane-reduce over m16
#pragma unroll
        for (int rt = 0; rt < 4; ++rt)
#pragma unroll
            for (int i = 0; i < 4; ++i) {
                int row = rt * 16 + 4 * q + i;
                float h1a = bf2f(h1s[row * LP + n1 + m16]);
                float h1b = bf2f(h1s[row * LP + n1 + 16 + m16]);
                float v = (1.0f - h1a * h1a) * g[rt][0][i]
                        + (1.0f - h1b * h1b) * g[rt][1][i];
                v += __shfl_xor(v, 1, 64);
                v += __shfl_xor(v, 2, 64);
                v += __shfl_xor(v, 4, 64);
                v += __shfl_xor(v, 8, 64);
                if (m16 == 0) divacc[w][row] = v;
            }
    }
    __syncthreads();

    if (tid < MROWS) {
        float s = 0.0f;
#pragma unroll
        for (int ww = 0; ww < 16; ++ww) s += divacc[ww][tid];
        out[(r0 + tid) * (DD + 1) + DD] = s;
    }
}

extern "C" void kernel_launch(void* const* d_in, const int* in_sizes, int n_in,
                              void* d_out, int out_size, void* d_ws, size_t ws_size,
                              hipStream_t stream) {
    const float* t  = (const float*)d_in[0];
    const float* x  = (const float*)d_in[1];
    const float* W1 = (const float*)d_in[2];
    const float* b1 = (const float*)d_in[3];
    const float* W2 = (const float*)d_in[4];
    const float* b2 = (const float*)d_in[5];
    const float* W3 = (const float*)d_in[6];
    const float* b3 = (const float*)d_in[7];
    float* out = (float*)d_out;

    u16*   ws16 = (u16*)d_ws;
    float* z0   = (float*)((char*)d_ws + OFF_Z0B);

    precompute<<<137, 256, 0, stream>>>(t, W1, b1, W2, W3, ws16, z0);
    cnf_main<<<8192 / MROWS, TPB, 0, stream>>>(x, ws16, z0, b2, b3, out);
}

// Round 7
// 91.282 us; speedup vs baseline: 1.0764x; 1.0764x over previous
//
#include <hip/hip_runtime.h>

#define HH 512
#define DD 64
#define MROWS 32
#define TPB 1024
#define LP 520            // u16 pitch for 32x512 LDS tiles

typedef unsigned short u16;
typedef short s16x8 __attribute__((ext_vector_type(8)));   // 8 bf16 = 4 VGPRs
typedef float f32x4 __attribute__((ext_vector_type(4)));

#define MFMA16(A,B,C) __builtin_amdgcn_mfma_f32_16x16x32_bf16((A),(B),(C),0,0,0)

// ---- workspace layout (u16 element offsets), fragment-linear:
//   addr = ntile*16*K + ks*512 + lane*8 ; value[j] = M[k = ks*32+(lane>>4)*8+j][n = nt*16+(lane&15)]
#define OFF_EF   0
#define OFF_W2F  (HH*HH)
#define OFF_W1F  (2*HH*HH)
#define OFF_W3F  (2*HH*HH + HH*DD)
#define OFF_Z0B  ((2*HH*HH + 2*HH*DD)*2)   // byte offset of z0 (f32[512])

__device__ __forceinline__ u16 f2bf(float f) {
    unsigned u = __builtin_bit_cast(unsigned, f);
    u += 0x7fffu + ((u >> 16) & 1u);
    return (u16)(u >> 16);
}
__device__ __forceinline__ float bf2f(u16 h) {
    return __builtin_bit_cast(float, (unsigned)h << 16);
}
__device__ __forceinline__ float fast_tanh(float x) {
    float e = __expf(2.0f * x);
    return 1.0f - 2.0f * __builtin_amdgcn_rcpf(e + 1.0f);
}

// =======================================================================
// precompute: 137 blocks x 256 threads (unchanged from R4 — ~4 us)
// =======================================================================
__global__ __launch_bounds__(256) void precompute(
    const float* __restrict__ t,  const float* __restrict__ W1,
    const float* __restrict__ b1, const float* __restrict__ W2,
    const float* __restrict__ W3, u16* __restrict__ ws16, float* __restrict__ z0)
{
    __shared__ float T[16 * 264 > 256 * 20 ? 16 * 264 : 256 * 20];
    u16* Ef  = ws16 + OFF_EF;
    u16* W2f = ws16 + OFF_W2F;
    u16* W1f = ws16 + OFF_W1F;
    u16* W3f = ws16 + OFF_W3F;

    const int bid = blockIdx.x, tid = threadIdx.x;
    const int lane = tid & 63, wv = tid >> 6;
    const int m16 = lane & 15, q = lane >> 4;

    if (bid < 64) {
        const int nt = bid >> 1, bh = bid & 1;
        const int a0 = nt * 16, b0 = bh * 256;
        s16x8 afh[2], afl[2];
#pragma unroll
        for (int h = 0; h < 2; ++h)
#pragma unroll
            for (int j = 0; j < 8; ++j) {
                int i = h * 32 + q * 8 + j;
                float v = W1[(1 + i) * HH + a0 + m16];
                u16 hi = f2bf(v);
                afh[h][j] = (short)hi;
                afl[h][j] = (short)f2bf(v - bf2f(hi));
            }
#pragma unroll
        for (int bt = 0; bt < 4; ++bt) {
            int bl = wv * 64 + bt * 16;
            s16x8 bfh[2], bfl[2];
#pragma unroll
            for (int h = 0; h < 2; ++h) {
                const float* src = W3 + (b0 + bl + m16) * DD + h * 32 + q * 8;
                float4 p0 = *(const float4*)(src);
                float4 p1 = *(const float4*)(src + 4);
                float vv[8] = {p0.x,p0.y,p0.z,p0.w,p1.x,p1.y,p1.z,p1.w};
#pragma unroll
                for (int j = 0; j < 8; ++j) {
                    u16 hi = f2bf(vv[j]);
                    bfh[h][j] = (short)hi;
                    bfl[h][j] = (short)f2bf(vv[j] - bf2f(hi));
                }
            }
            f32x4 c = {0.f, 0.f, 0.f, 0.f};
#pragma unroll
            for (int h = 0; h < 2; ++h) {
                c = MFMA16(afh[h], bfh[h], c);
                c = MFMA16(afh[h], bfl[h], c);
                c = MFMA16(afl[h], bfh[h], c);
            }
#pragma unroll
            for (int r = 0; r < 4; ++r)
                T[(4 * q + r) * 264 + bl + m16] = c[r];
        }
        __syncthreads();
#pragma unroll
        for (int p = 0; p < 2; ++p) {
            int ksl = p * 4 + wv;
            int al  = m16;
            int blc = ksl * 32 + q * 8;
            const float* w2p = W2 + (a0 + al) * HH + b0 + blc;
            float4 wa = *(const float4*)(w2p), wb = *(const float4*)(w2p + 4);
            const float* glp = T + al * 264 + blc;
            s16x8 o;
            o[0]=(short)f2bf(wa.x*glp[0]); o[1]=(short)f2bf(wa.y*glp[1]);
            o[2]=(short)f2bf(wa.z*glp[2]); o[3]=(short)f2bf(wa.w*glp[3]);
            o[4]=(short)f2bf(wb.x*glp[4]); o[5]=(short)f2bf(wb.y*glp[5]);
            o[6]=(short)f2bf(wb.z*glp[6]); o[7]=(short)f2bf(wb.w*glp[7]);
            *(s16x8*)(Ef + nt * 8192 + (b0 / 32 + ksl) * 512 + lane * 8) = o;
        }
        if (bh == 0 && tid < 128) {
            int ks = tid >> 6, ln = tid & 63;
            int n  = nt * 16 + (ln & 15);
            int k0 = ks * 32 + (ln >> 4) * 8;
            s16x8 o;
#pragma unroll
            for (int j = 0; j < 8; ++j) o[j] = (short)f2bf(W1[(1 + k0 + j) * HH + n]);
            *(s16x8*)(W1f + nt * 1024 + ks * 512 + ln * 8) = o;
        }
    } else if (bid < 128) {
        const int nt = (bid - 64) >> 1, kh = (bid - 64) & 1;
        const int n0 = nt * 16, k0 = kh * 256;
#pragma unroll
        for (int it = 0; it < 4; ++it) {
            int r = (tid >> 2) + it * 64;
            int c = (tid & 3) * 4;
            float4 v = *(const float4*)(W2 + (k0 + r) * HH + n0 + c);
            *(float4*)(T + r * 20 + c) = v;
        }
        __syncthreads();
#pragma unroll
        for (int p = 0; p < 2; ++p) {
            int ksl = p * 4 + wv;
            int kq  = ksl * 32 + q * 8;
            s16x8 o;
#pragma unroll
            for (int j = 0; j < 8; ++j) o[j] = (short)f2bf(T[(kq + j) * 20 + m16]);
            *(s16x8*)(W2f + nt * 8192 + (k0 / 32 + ksl) * 512 + lane * 8) = o;
        }
    } else if (bid < 136) {
        const int ot = (bid - 128) >> 1, kh = (bid - 128) & 1;
        const int o0 = ot * 16, k0 = kh * 256;
#pragma unroll
        for (int it = 0; it < 4; ++it) {
            int r = (tid >> 2) + it * 64;
            int c = (tid & 3) * 4;
            float4 v = *(const float4*)(W3 + (k0 + r) * DD + o0 + c);
            *(float4*)(T + r * 20 + c) = v;
        }
        __syncthreads();
#pragma unroll
        for (int p = 0; p < 2; ++p) {
            int ksl = p * 4 + wv;
            int kq  = ksl * 32 + q * 8;
            s16x8 o;
#pragma unroll
            for (int j = 0; j < 8; ++j) o[j] = (short)f2bf(T[(kq + j) * 20 + m16]);
            *(s16x8*)(W3f + ot * 8192 + (k0 / 32 + ksl) * 512 + lane * 8) = o;
        }
    } else {
        for (int n = tid; n < HH; n += 256)
            z0[n] = b1[n] + t[0] * W1[n];
    }
}

// =======================================================================
// cnf_main: 256 blocks x 1024 threads — R5 structure + per-block
// address decorrelation (k-phase rotation + n-tile rotation) to break
// cross-CU lockstep on identical L2 lines.
// =======================================================================
__global__ __launch_bounds__(TPB) void cnf_main(
    const float* __restrict__ x,  const u16* __restrict__ ws16,
    const float* __restrict__ z0, const float* __restrict__ b2,
    const float* __restrict__ b3, float* __restrict__ out)
{
    __shared__ u16 h1s[MROWS * LP];
    __shared__ u16 h2s[MROWS * LP];
    __shared__ u16 d2s[MROWS * LP];     // low bytes double as xs before phase 2
    __shared__ float z0s[HH];
    __shared__ float b2s[HH];
    __shared__ float b3s[DD];
    __shared__ float divacc[16][MROWS];

    const u16* Ef  = ws16 + OFF_EF;
    const u16* W2f = ws16 + OFF_W2F;
    const u16* W1f = ws16 + OFF_W1F;
    const u16* W3f = ws16 + OFF_W3F;

    const int tid  = threadIdx.x;
    const int lane = tid & 63;
    const int w    = tid >> 6;        // 16 waves
    const int m16  = lane & 15;
    const int q    = lane >> 4;
    const int kq   = q * 8;
    const int r0   = blockIdx.x * MROWS;

    // decorrelation keys: co-XCD blocks (stride 8 under round-robin) differ
    const int noff = (blockIdx.x >> 3) & 31;
    const int koff = (blockIdx.x >> 3) & 15;

    // wave's two n-tiles (a permutation of 0..31 across (w,ct))
    const int tile0 = (2 * w + noff) & 31;
    const int tile1 = (2 * w + 1 + noff) & 31;
    const int col0  = tile0 * 16 + m16;
    const int col1  = tile1 * 16 + m16;

    u16* xs = d2s;                    // overlap: xs dead after phase 1

    // ---- top-of-kernel global prefetch: W1f frags + phase-2 first 4 k-steps ----
    s16x8 p1b[2][2];
    {
        const u16* bb0 = W1f + tile0 * 1024 + lane * 8;
        const u16* bb1 = W1f + tile1 * 1024 + lane * 8;
        p1b[0][0] = *(const s16x8*)(bb0);
        p1b[0][1] = *(const s16x8*)(bb0 + 512);
        p1b[1][0] = *(const s16x8*)(bb1);
        p1b[1][1] = *(const s16x8*)(bb1 + 512);
    }
    const u16* w2bp0 = W2f + tile0 * 8192 + lane * 8;
    const u16* w2bp1 = W2f + tile1 * 8192 + lane * 8;
    s16x8 B0[4], B1[4];
#pragma unroll
    for (int k = 0; k < 4; ++k) {
        const int kk = (koff + k) & 15;
        B0[k] = *(const s16x8*)(w2bp0 + kk * 512);
        B1[k] = *(const s16x8*)(w2bp1 + kk * 512);
    }

    // ---- stage ----
    for (int idx = tid; idx < MROWS * DD; idx += TPB) {
        int r = idx >> 6, c = idx & 63;
        xs[r * 72 + c] = f2bf(x[(r0 + r) * (DD + 1) + c]);
    }
    if (tid < HH) { z0s[tid] = z0[tid]; b2s[tid] = b2[tid]; }
    if (tid < DD) b3s[tid] = b3[tid];
    __syncthreads();

    float d1reg[2][2][4];             // d1 = 1-h1^2, kept in regs for phase 4

    // ---- phase 1: h1 = tanh([t,x]@W1 + z0), K=64 ----
    {
        s16x8 xa[2][2];
#pragma unroll
        for (int rt = 0; rt < 2; ++rt)
#pragma unroll
            for (int h = 0; h < 2; ++h)
                xa[rt][h] = *(const s16x8*)(xs + (rt * 16 + m16) * 72 + h * 32 + kq);
#pragma unroll
        for (int ct = 0; ct < 2; ++ct) {
            int col = ct ? col1 : col0;
#pragma unroll
            for (int rt = 0; rt < 2; ++rt) {
                f32x4 c = {0.f, 0.f, 0.f, 0.f};
                c = MFMA16(xa[rt][0], p1b[ct][0], c);
                c = MFMA16(xa[rt][1], p1b[ct][1], c);
#pragma unroll
                for (int i = 0; i < 4; ++i) {
                    float hv = fast_tanh(c[i] + z0s[col]);
                    h1s[(rt * 16 + 4 * q + i) * LP + col] = f2bf(hv);
                    d1reg[rt][ct][i] = 1.0f - hv * hv;
                }
            }
        }
    }
    __syncthreads();

    // ---- phase 2: h2 = tanh(h1@W2 + b2), rotated k-order ----
    f32x4 a00={0,0,0,0}, a01={0,0,0,0}, a10={0,0,0,0}, a11={0,0,0,0};
    {
        const u16* ap0 = h1s + m16 * LP + kq;
        const u16* ap1 = h1s + (16 + m16) * LP + kq;
#pragma unroll
        for (int ks = 0; ks < 16; ++ks) {
            const int kk = (koff + ks) & 15;
            s16x8 f0 = *(const s16x8*)(ap0 + kk * 32);
            s16x8 f1 = *(const s16x8*)(ap1 + kk * 32);
            const int sl = ks & 3;
            a00 = MFMA16(f0, B0[sl], a00);
            a10 = MFMA16(f1, B0[sl], a10);
            a01 = MFMA16(f0, B1[sl], a01);
            a11 = MFMA16(f1, B1[sl], a11);
            if (ks < 12) {
                const int kn = (koff + ks + 4) & 15;
                B0[sl] = *(const s16x8*)(w2bp0 + kn * 512);
                B1[sl] = *(const s16x8*)(w2bp1 + kn * 512);
            }
        }
    }

    // ---- issue phase-4 Ef preloads (depth 2) before epilogue/barrier ----
    const u16* efp0 = Ef + tile0 * 8192 + lane * 8;
    const u16* efp1 = Ef + tile1 * 8192 + lane * 8;
    s16x8 E0[4], E1[4];
#pragma unroll
    for (int k = 0; k < 2; ++k) {
        const int kk = (koff + k) & 15;
        E0[k] = *(const s16x8*)(efp0 + kk * 512);
        E1[k] = *(const s16x8*)(efp1 + kk * 512);
    }

    // ---- phase-2 epilogue: tanh -> h2s, d2 -> d2s ----
    {
        f32x4 acc[2][2] = {{a00, a01}, {a10, a11}};
#pragma unroll
        for (int rt = 0; rt < 2; ++rt)
#pragma unroll
            for (int ct = 0; ct < 2; ++ct) {
                int col = ct ? col1 : col0;
#pragma unroll
                for (int i = 0; i < 4; ++i) {
                    int row = rt * 16 + 4 * q + i;
                    float hv = fast_tanh(acc[rt][ct][i] + b2s[col]);
                    h2s[row * LP + col] = f2bf(hv);
                    d2s[row * LP + col] = f2bf(1.0f - hv * hv);
                }
            }
    }
    __syncthreads();

    // ---- phase 3 (waves 0..7): dx = h2@W3 + b3, rotated ot & k ----
    if (w < 8) {
        const int rowt = w >> 2;
        const int ot   = (w + noff) & 3;
        const u16* ap = h2s + (rowt * 16 + m16) * LP + kq;
        const u16* bp = W3f + ot * 8192 + lane * 8;
        s16x8 W3r[4];
#pragma unroll
        for (int k = 0; k < 4; ++k)
            W3r[k] = *(const s16x8*)(bp + ((koff + k) & 15) * 512);
        f32x4 cA = {0.f,0.f,0.f,0.f}, cB = {0.f,0.f,0.f,0.f};
#pragma unroll
        for (int ks = 0; ks < 16; ++ks) {
            const int kk = (koff + ks) & 15;
            s16x8 f = *(const s16x8*)(ap + kk * 32);
            const int sl = ks & 3;
            if (ks & 1) cB = MFMA16(f, W3r[sl], cB);
            else        cA = MFMA16(f, W3r[sl], cA);
            if (ks < 12) W3r[sl] = *(const s16x8*)(bp + ((koff + ks + 4) & 15) * 512);
        }
        f32x4 c3 = cA + cB;
        int o = ot * 16 + m16;
#pragma unroll
        for (int i = 0; i < 4; ++i)
            out[(r0 + rowt * 16 + 4 * q + i) * (DD + 1) + o] = c3[i] + b3s[o];
    }

    // ---- phase 4 (all 16 waves): M = d2@Ef; div = sum d1 .* M ----
    {
        f32x4 g00={0,0,0,0}, g01={0,0,0,0}, g10={0,0,0,0}, g11={0,0,0,0};
        const u16* ap0 = d2s + m16 * LP + kq;
        const u16* ap1 = d2s + (16 + m16) * LP + kq;
#pragma unroll
        for (int ks = 0; ks < 16; ++ks) {
            const int kk = (koff + ks) & 15;
            s16x8 f0 = *(const s16x8*)(ap0 + kk * 32);
            s16x8 f1 = *(const s16x8*)(ap1 + kk * 32);
            const int sl = ks & 3;
            g00 = MFMA16(f0, E0[sl], g00);
            g10 = MFMA16(f1, E0[sl], g10);
            g01 = MFMA16(f0, E1[sl], g01);
            g11 = MFMA16(f1, E1[sl], g11);
            if (ks < 14) {
                const int dl = (ks + 2) & 3;
                const int kn = (koff + ks + 2) & 15;
                E0[dl] = *(const s16x8*)(efp0 + kn * 512);
                E1[dl] = *(const s16x8*)(efp1 + kn * 512);
            }
        }
        f32x4 acc[2][2] = {{g00, g01}, {g10, g11}};
#pragma unroll
        for (int rt = 0; rt < 2; ++rt)
#pragma unroll
            for (int i = 0; i < 4; ++i) {
                float v = d1reg[rt][0][i] * acc[rt][0][i]
                        + d1reg[rt][1][i] * acc[rt][1][i];
                v += __shfl_xor(v, 1, 64);
                v += __shfl_xor(v, 2, 64);
                v += __shfl_xor(v, 4, 64);
                v += __shfl_xor(v, 8, 64);
                if (m16 == 0) divacc[w][rt * 16 + 4 * q + i] = v;
            }
    }
    __syncthreads();

    if (tid < MROWS) {
        float s = 0.0f;
#pragma unroll
        for (int ww = 0; ww < 16; ++ww) s += divacc[ww][tid];
        out[(r0 + tid) * (DD + 1) + DD] = s;
    }
}

extern "C" void kernel_launch(void* const* d_in, const int* in_sizes, int n_in,
                              void* d_out, int out_size, void* d_ws, size_t ws_size,
                              hipStream_t stream) {
    const float* t  = (const float*)d_in[0];
    const float* x  = (const float*)d_in[1];
    const float* W1 = (const float*)d_in[2];
    const float* b1 = (const float*)d_in[3];
    const float* W2 = (const float*)d_in[4];
    const float* b2 = (const float*)d_in[5];
    const float* W3 = (const float*)d_in[6];
    const float* b3 = (const float*)d_in[7];
    float* out = (float*)d_out;

    u16*   ws16 = (u16*)d_ws;
    float* z0   = (float*)((char*)d_ws + OFF_Z0B);

    precompute<<<137, 256, 0, stream>>>(t, W1, b1, W2, W3, ws16, z0);
    cnf_main<<<8192 / MROWS, TPB, 0, stream>>>(x, ws16, z0, b2, b3, out);
}